// Round 1
// baseline (1187.604 us; speedup 1.0000x reference)
//
#include <hip/hip_runtime.h>
#include <math.h>

#define NG 100000
#define ND 50000
#define DIM 128
#define NE 800000
#define EPSN 1e-12f

// ---------------- CSR build helpers ----------------

__global__ void zero_ints(int* __restrict__ p, int n) {
  int i = blockIdx.x * 256 + threadIdx.x;
  if (i < n) p[i] = 0;
}

__global__ void count_deg(const int* __restrict__ dst, int* __restrict__ deg, int n) {
  int i = blockIdx.x * 256 + threadIdx.x;
  if (i < n) atomicAdd(&deg[dst[i]], 1);
}

__global__ void block_partials(const int* __restrict__ deg, int* __restrict__ part, int n) {
  __shared__ int s[256];
  int i = blockIdx.x * 256 + threadIdx.x;
  s[threadIdx.x] = (i < n) ? deg[i] : 0;
  __syncthreads();
  for (int st = 128; st > 0; st >>= 1) {
    if (threadIdx.x < st) s[threadIdx.x] += s[threadIdx.x + st];
    __syncthreads();
  }
  if (threadIdx.x == 0) part[blockIdx.x] = s[0];
}

// single block, 512 threads; exclusive scan of part[0..nb)
__global__ void scan_partials(int* __restrict__ part, int nb) {
  __shared__ int s[512];
  int t = threadIdx.x;
  s[t] = (t < nb) ? part[t] : 0;
  __syncthreads();
  for (int off = 1; off < 512; off <<= 1) {
    int v = (t >= off) ? s[t - off] : 0;
    __syncthreads();
    s[t] += v;
    __syncthreads();
  }
  if (t < nb) part[t] = (t > 0) ? s[t - 1] : 0;
}

// deg_cur holds degrees on entry; on exit off[i] = exclusive prefix, off[n] = total,
// deg_cur[i] = same exclusive prefix (used as fill cursor).
__global__ void finalize_scan(int* __restrict__ deg_cur, const int* __restrict__ part,
                              int* __restrict__ off, int n, int total) {
  __shared__ int s[256];
  int t = threadIdx.x;
  int i = blockIdx.x * 256 + t;
  int d = (i < n) ? deg_cur[i] : 0;
  s[t] = d;
  __syncthreads();
  for (int o = 1; o < 256; o <<= 1) {
    int v = (t >= o) ? s[t - o] : 0;
    __syncthreads();
    s[t] += v;
    __syncthreads();
  }
  int excl = s[t] - d + part[blockIdx.x];
  if (i < n) {
    off[i] = excl;
    deg_cur[i] = excl;
    if (i == n - 1) off[n] = total;
  }
}

__global__ void fill_csr(const int* __restrict__ src, const int* __restrict__ dst,
                         int* __restrict__ cur, int* __restrict__ csr, int n) {
  int i = blockIdx.x * 256 + threadIdx.x;
  if (i < n) {
    int p = atomicAdd(&cur[dst[i]], 1);
    csr[p] = src[i];
  }
}

// ---------------- mean aggregation: one wave per dst node ----------------

__global__ void agg_mean(const float* __restrict__ xsrc, const int* __restrict__ off,
                         const int* __restrict__ csr, float* __restrict__ agg, int ndst) {
  int wid = (blockIdx.x * blockDim.x + threadIdx.x) >> 6;
  int lane = threadIdx.x & 63;
  if (wid >= ndst) return;
  int e0 = off[wid], e1 = off[wid + 1];
  const float2* xs = (const float2*)xsrc;
  float ax = 0.f, ay = 0.f;
  int e = e0;
  for (; e + 1 < e1; e += 2) {
    int s0 = csr[e], s1 = csr[e + 1];
    float2 a = xs[(size_t)s0 * 64 + lane];
    float2 b = xs[(size_t)s1 * 64 + lane];
    ax += a.x + b.x;
    ay += a.y + b.y;
  }
  if (e < e1) {
    float2 a = xs[(size_t)csr[e] * 64 + lane];
    ax += a.x;
    ay += a.y;
  }
  float inv = (e1 > e0) ? 1.f / (float)(e1 - e0) : 0.f;
  float2 m;
  m.x = ax * inv;
  m.y = ay * inv;
  ((float2*)agg)[(size_t)wid * 64 + lane] = m;
}

// ---------------- fused SAGE update: H = agg*Wl^T + x*Wr^T + b, (relu), l2norm, +x ----------------
// 64 rows x 128 cols per block, 256 threads, 8x4 microtile. out may alias x (row-wise in-place).

__launch_bounds__(256)
__global__ void sage_update(const float* __restrict__ agg, const float* __restrict__ x,
                            const float* __restrict__ Wl, const float* __restrict__ Wr,
                            const float* __restrict__ bias, float* __restrict__ out,
                            int n, int relu) {
  __shared__ float sA[16][68];    // agg tile, [k][row]
  __shared__ float sX[16][68];    // x tile, [k][row]
  __shared__ float sWl[16][132];  // [k][col]
  __shared__ float sWr[16][132];

  int tid = threadIdx.x;
  int r0g = blockIdx.x * 64;
  int tcol = tid & 31;  // col quad index: cols tcol*4 .. +3
  int trow = tid >> 5;  // 0..7 : rows trow*8 .. +7

  float acc[8][4];
#pragma unroll
  for (int r = 0; r < 8; r++)
#pragma unroll
    for (int c = 0; c < 4; c++) acc[r][c] = 0.f;

  // staging maps
  int a_row = tid >> 2;        // 0..63
  int a_kq = (tid & 3) * 4;    // 0,4,8,12
  int w_c = tid & 127;         // 0..127
  int w_kq = (tid >> 7) * 8;   // 0 or 8
  int ar_g = r0g + a_row;
  if (ar_g >= n) ar_g = n - 1;  // clamp; stores are guarded

  for (int k0 = 0; k0 < 128; k0 += 16) {
    float4 va = *(const float4*)&agg[(size_t)ar_g * DIM + k0 + a_kq];
    float4 vx = *(const float4*)&x[(size_t)ar_g * DIM + k0 + a_kq];
    float4 wl0 = *(const float4*)&Wl[(size_t)w_c * DIM + k0 + w_kq];
    float4 wl1 = *(const float4*)&Wl[(size_t)w_c * DIM + k0 + w_kq + 4];
    float4 wr0 = *(const float4*)&Wr[(size_t)w_c * DIM + k0 + w_kq];
    float4 wr1 = *(const float4*)&Wr[(size_t)w_c * DIM + k0 + w_kq + 4];
    __syncthreads();  // prior iteration's LDS reads complete before overwrite
    sA[a_kq + 0][a_row] = va.x;
    sA[a_kq + 1][a_row] = va.y;
    sA[a_kq + 2][a_row] = va.z;
    sA[a_kq + 3][a_row] = va.w;
    sX[a_kq + 0][a_row] = vx.x;
    sX[a_kq + 1][a_row] = vx.y;
    sX[a_kq + 2][a_row] = vx.z;
    sX[a_kq + 3][a_row] = vx.w;
    sWl[w_kq + 0][w_c] = wl0.x;
    sWl[w_kq + 1][w_c] = wl0.y;
    sWl[w_kq + 2][w_c] = wl0.z;
    sWl[w_kq + 3][w_c] = wl0.w;
    sWl[w_kq + 4][w_c] = wl1.x;
    sWl[w_kq + 5][w_c] = wl1.y;
    sWl[w_kq + 6][w_c] = wl1.z;
    sWl[w_kq + 7][w_c] = wl1.w;
    sWr[w_kq + 0][w_c] = wr0.x;
    sWr[w_kq + 1][w_c] = wr0.y;
    sWr[w_kq + 2][w_c] = wr0.z;
    sWr[w_kq + 3][w_c] = wr0.w;
    sWr[w_kq + 4][w_c] = wr1.x;
    sWr[w_kq + 5][w_c] = wr1.y;
    sWr[w_kq + 6][w_c] = wr1.z;
    sWr[w_kq + 7][w_c] = wr1.w;
    __syncthreads();

#pragma unroll
    for (int kk = 0; kk < 16; kk++) {
      float4 wl = *(const float4*)&sWl[kk][tcol * 4];
      float4 wr = *(const float4*)&sWr[kk][tcol * 4];
      float4 am0 = *(const float4*)&sA[kk][trow * 8];
      float4 am1 = *(const float4*)&sA[kk][trow * 8 + 4];
      float4 ax0 = *(const float4*)&sX[kk][trow * 8];
      float4 ax1 = *(const float4*)&sX[kk][trow * 8 + 4];
      float am[8] = {am0.x, am0.y, am0.z, am0.w, am1.x, am1.y, am1.z, am1.w};
      float axv[8] = {ax0.x, ax0.y, ax0.z, ax0.w, ax1.x, ax1.y, ax1.z, ax1.w};
      float wlv[4] = {wl.x, wl.y, wl.z, wl.w};
      float wrv[4] = {wr.x, wr.y, wr.z, wr.w};
#pragma unroll
      for (int r = 0; r < 8; r++) {
#pragma unroll
        for (int c = 0; c < 4; c++) {
          acc[r][c] += am[r] * wlv[c] + axv[r] * wrv[c];
        }
      }
    }
  }

  // epilogue: bias, relu, l2 norm (across the 32 lanes sharing trow), skip add
  float4 bv = *(const float4*)&bias[tcol * 4];
  float bb[4] = {bv.x, bv.y, bv.z, bv.w};
  float ss[8];
#pragma unroll
  for (int r = 0; r < 8; r++) {
    float s2 = 0.f;
#pragma unroll
    for (int c = 0; c < 4; c++) {
      float h = acc[r][c] + bb[c];
      if (relu) h = fmaxf(h, 0.f);
      acc[r][c] = h;
      s2 += h * h;
    }
    ss[r] = s2;
  }
#pragma unroll
  for (int r = 0; r < 8; r++) {
    float v = ss[r];
    v += __shfl_xor(v, 1);
    v += __shfl_xor(v, 2);
    v += __shfl_xor(v, 4);
    v += __shfl_xor(v, 8);
    v += __shfl_xor(v, 16);
    ss[r] = v;
  }
#pragma unroll
  for (int r = 0; r < 8; r++) {
    int row = r0g + trow * 8 + r;
    if (row < n) {
      float inv = 1.f / fmaxf(sqrtf(ss[r]), EPSN);
      float4 xv = *(const float4*)&x[(size_t)row * DIM + tcol * 4];
      float4 o;
      o.x = acc[r][0] * inv + xv.x;
      o.y = acc[r][1] * inv + xv.y;
      o.z = acc[r][2] * inv + xv.z;
      o.w = acc[r][3] * inv + xv.w;
      *(float4*)&out[(size_t)row * DIM + tcol * 4] = o;
    }
  }
}

// ---------------- launch ----------------

extern "C" void kernel_launch(void* const* d_in, const int* in_sizes, int n_in,
                              void* d_out, int out_size, void* d_ws, size_t ws_size,
                              hipStream_t stream) {
  const float* xg0 = (const float*)d_in[0];
  const float* xd0 = (const float*)d_in[1];
  const float* Wl = (const float*)d_in[2];   // [L,2,D,D]
  const float* Wr = (const float*)d_in[3];
  const float* bs = (const float*)d_in[4];   // [L,2,D]
  const int* src_g2d = (const int*)d_in[5];
  const int* dst_g2d = (const int*)d_in[6];
  const int* src_d2g = (const int*)d_in[7];
  const int* dst_d2g = (const int*)d_in[8];

  float* out_xg = (float*)d_out;                       // [NG*D]
  float* out_xd = (float*)d_out + (size_t)NG * DIM;    // [ND*D]

  // workspace carve-up (~85 MB total)
  char* p = (char*)d_ws;
  auto alloc = [&](size_t bytes) -> char* {
    char* q = p;
    p += (bytes + 255) & ~(size_t)255;
    return q;
  };
  int* off_d = (int*)alloc((ND + 1) * 4);
  int* off_g = (int*)alloc((NG + 1) * 4);
  int* cur_d = (int*)alloc((size_t)ND * 4);
  int* cur_g = (int*)alloc((size_t)NG * 4);
  int* part = (int*)alloc(512 * 4);
  int* csr_d = (int*)alloc((size_t)NE * 4);  // gene srcs grouped by disease dst
  int* csr_g = (int*)alloc((size_t)NE * 4);  // disease srcs grouped by gene dst
  float* agg_d = (float*)alloc((size_t)ND * DIM * 4);
  float* agg_g = (float*)alloc((size_t)NG * DIM * 4);

  const int TB = 256;
  int nbE = (NE + TB - 1) / TB;
  int nbD = (ND + TB - 1) / TB;  // 196
  int nbG = (NG + TB - 1) / TB;  // 391

  // ---- CSR build (edge lists are layer-invariant: build once per call) ----
  zero_ints<<<nbD, TB, 0, stream>>>(cur_d, ND);
  zero_ints<<<nbG, TB, 0, stream>>>(cur_g, NG);
  count_deg<<<nbE, TB, 0, stream>>>(dst_g2d, cur_d, NE);
  count_deg<<<nbE, TB, 0, stream>>>(dst_d2g, cur_g, NE);

  block_partials<<<nbD, TB, 0, stream>>>(cur_d, part, ND);
  scan_partials<<<1, 512, 0, stream>>>(part, nbD);
  finalize_scan<<<nbD, TB, 0, stream>>>(cur_d, part, off_d, ND, NE);
  fill_csr<<<nbE, TB, 0, stream>>>(src_g2d, dst_g2d, cur_d, csr_d, NE);

  block_partials<<<nbG, TB, 0, stream>>>(cur_g, part, NG);
  scan_partials<<<1, 512, 0, stream>>>(part, nbG);
  finalize_scan<<<nbG, TB, 0, stream>>>(cur_g, part, off_g, NG, NE);
  fill_csr<<<nbE, TB, 0, stream>>>(src_d2g, dst_d2g, cur_g, csr_g, NE);

  int agD = (ND * 64 + TB - 1) / TB;  // 12500 blocks (wave per dst)
  int agG = (NG * 64 + TB - 1) / TB;  // 25000 blocks
  int upD = (ND + 63) / 64;           // 782
  int upG = (NG + 63) / 64;           // 1563

  // ---- layer 0 (relu) : reads d_in, writes d_out (doubles as x_cur) ----
  agg_mean<<<agD, TB, 0, stream>>>(xg0, off_d, csr_d, agg_d, ND);
  agg_mean<<<agG, TB, 0, stream>>>(xd0, off_g, csr_g, agg_g, NG);
  sage_update<<<upD, TB, 0, stream>>>(agg_d, xd0, Wl + 0 * DIM * DIM, Wr + 0 * DIM * DIM,
                                      bs + 0 * DIM, out_xd, ND, 1);
  sage_update<<<upG, TB, 0, stream>>>(agg_g, xg0, Wl + 1 * DIM * DIM, Wr + 1 * DIM * DIM,
                                      bs + 1 * DIM, out_xg, NG, 1);

  // ---- layer 1 (no relu) : in-place on d_out ----
  agg_mean<<<agD, TB, 0, stream>>>(out_xg, off_d, csr_d, agg_d, ND);
  agg_mean<<<agG, TB, 0, stream>>>(out_xd, off_g, csr_g, agg_g, NG);
  sage_update<<<upD, TB, 0, stream>>>(agg_d, out_xd, Wl + 2 * DIM * DIM, Wr + 2 * DIM * DIM,
                                      bs + 2 * DIM, out_xd, ND, 0);
  sage_update<<<upG, TB, 0, stream>>>(agg_g, out_xg, Wl + 3 * DIM * DIM, Wr + 3 * DIM * DIM,
                                      bs + 3 * DIM, out_xg, NG, 0);
}

// Round 2
// 656.476 us; speedup vs baseline: 1.8091x; 1.8091x over previous
//
#include <hip/hip_runtime.h>
#include <math.h>

#define NG 100000
#define ND 50000
#define DIM 128
#define NE 800000
#define EPSN 1e-12f

#define NBT_D 391  // ceil(ND/128)
#define NBT_G 782  // ceil(NG/128)

typedef __bf16 bf16x8 __attribute__((ext_vector_type(8)));
typedef float f32x4 __attribute__((ext_vector_type(4)));
typedef unsigned int uint32;

// ---------------- CSR build helpers ----------------

__global__ void zero_ints(int* __restrict__ p, int n) {
  int i = blockIdx.x * 256 + threadIdx.x;
  if (i < n) p[i] = 0;
}

__global__ void count_deg(const int* __restrict__ dst, int* __restrict__ deg, int n) {
  int i = blockIdx.x * 256 + threadIdx.x;
  if (i < n) atomicAdd(&deg[dst[i]], 1);
}

__global__ void block_partials(const int* __restrict__ deg, int* __restrict__ part, int n) {
  __shared__ int s[256];
  int i = blockIdx.x * 256 + threadIdx.x;
  s[threadIdx.x] = (i < n) ? deg[i] : 0;
  __syncthreads();
  for (int st = 128; st > 0; st >>= 1) {
    if (threadIdx.x < st) s[threadIdx.x] += s[threadIdx.x + st];
    __syncthreads();
  }
  if (threadIdx.x == 0) part[blockIdx.x] = s[0];
}

__global__ void scan_partials(int* __restrict__ part, int nb) {
  __shared__ int s[512];
  int t = threadIdx.x;
  s[t] = (t < nb) ? part[t] : 0;
  __syncthreads();
  for (int off = 1; off < 512; off <<= 1) {
    int v = (t >= off) ? s[t - off] : 0;
    __syncthreads();
    s[t] += v;
    __syncthreads();
  }
  if (t < nb) part[t] = (t > 0) ? s[t - 1] : 0;
}

__global__ void finalize_scan(int* __restrict__ deg_cur, const int* __restrict__ part,
                              int* __restrict__ off, int n, int total) {
  __shared__ int s[256];
  int t = threadIdx.x;
  int i = blockIdx.x * 256 + t;
  int d = (i < n) ? deg_cur[i] : 0;
  s[t] = d;
  __syncthreads();
  for (int o = 1; o < 256; o <<= 1) {
    int v = (t >= o) ? s[t - o] : 0;
    __syncthreads();
    s[t] += v;
    __syncthreads();
  }
  int excl = s[t] - d + part[blockIdx.x];
  if (i < n) {
    off[i] = excl;
    deg_cur[i] = excl;
    if (i == n - 1) off[n] = total;
  }
}

__global__ void fill_csr(const int* __restrict__ src, const int* __restrict__ dst,
                         int* __restrict__ cur, int* __restrict__ csr, int n) {
  int i = blockIdx.x * 256 + threadIdx.x;
  if (i < n) {
    int p = atomicAdd(&cur[dst[i]], 1);
    csr[p] = src[i];
  }
}

// ---------------- W pre-split: fp32 -> bf16 hi + bf16 lo ----------------
// Wl, Wr are [4 sets][128][128] fp32 (set = layer*2 + edge_type)

__global__ void split_w(const float* __restrict__ Wl, const float* __restrict__ Wr,
                        ushort* __restrict__ WlH, ushort* __restrict__ WlL,
                        ushort* __restrict__ WrH, ushort* __restrict__ WrL) {
  int i = blockIdx.x * 256 + threadIdx.x;  // over 4*128*128 = 65536
  if (i >= 4 * 128 * 128) return;
  {
    float a = Wl[i];
    uint32 u = __builtin_bit_cast(uint32, a);
    ushort h = (ushort)(u >> 16);
    float hf = __builtin_bit_cast(float, u & 0xffff0000u);
    float r = a - hf;
    WlH[i] = h;
    WlL[i] = (ushort)(__builtin_bit_cast(uint32, r) >> 16);
  }
  {
    float a = Wr[i];
    uint32 u = __builtin_bit_cast(uint32, a);
    ushort h = (ushort)(u >> 16);
    float hf = __builtin_bit_cast(float, u & 0xffff0000u);
    float r = a - hf;
    WrH[i] = h;
    WrL[i] = (ushort)(__builtin_bit_cast(uint32, r) >> 16);
  }
}

// ---------------- mean aggregation: one wave per dst, 2 half-waves x float4 ----------------

__global__ void agg_dual(const float* __restrict__ xg, const float* __restrict__ xd,
                         const int* __restrict__ off_d, const int* __restrict__ csr_d,
                         float* __restrict__ agg_d,
                         const int* __restrict__ off_g, const int* __restrict__ csr_g,
                         float* __restrict__ agg_g) {
  int gw = (blockIdx.x * 256 + threadIdx.x) >> 6;
  int lane = threadIdx.x & 63;
  const float* xsrc;
  const int* off;
  const int* csr;
  float* agg;
  int node;
  if (gw < ND) {
    xsrc = xg; off = off_d; csr = csr_d; agg = agg_d; node = gw;
  } else {
    node = gw - ND;
    if (node >= NG) return;
    xsrc = xd; off = off_g; csr = csr_g; agg = agg_g;
  }
  int e0 = off[node], e1 = off[node + 1];
  int half = lane >> 5, l32 = lane & 31;
  const float4* xs = (const float4*)xsrc;
  float ax = 0.f, ay = 0.f, az = 0.f, aw = 0.f;
  int e = e0 + half;
  for (; e + 2 < e1; e += 4) {  // 2 edges per half per iter -> 4 float4 loads in flight/wave
    int s0 = csr[e], s1 = csr[e + 2];
    float4 a = xs[(size_t)s0 * 32 + l32];
    float4 b = xs[(size_t)s1 * 32 + l32];
    ax += a.x + b.x;
    ay += a.y + b.y;
    az += a.z + b.z;
    aw += a.w + b.w;
  }
  if (e < e1) {
    float4 a = xs[(size_t)csr[e] * 32 + l32];
    ax += a.x;
    ay += a.y;
    az += a.z;
    aw += a.w;
  }
  ax += __shfl_xor(ax, 32);
  ay += __shfl_xor(ay, 32);
  az += __shfl_xor(az, 32);
  aw += __shfl_xor(aw, 32);
  if (half == 0) {
    int deg = e1 - e0;
    float inv = (deg > 0) ? 1.f / (float)deg : 0.f;
    float4 m;
    m.x = ax * inv;
    m.y = ay * inv;
    m.z = az * inv;
    m.w = aw * inv;
    ((float4*)agg)[(size_t)node * 32 + l32] = m;
  }
}

// ---------------- split-bf16 MFMA SAGE update ----------------
// Per block: 128 rows x 128 cols. 4 waves, wave w owns rows [w*32, w*32+32), all cols.
// C = agg*Wl^T + x*Wr^T via K=128 phases; split-bf16: Ah*Wh + Ah*Wl + Al*Wh.
// Epilogue: +bias, (relu), row l2-norm, skip-add x. out may alias x (block-local rows only).

__device__ __forceinline__ void cvt_split(const float* p, bf16x8& hi, bf16x8& lo) {
  float4 a = *(const float4*)p;
  float4 b = *(const float4*)(p + 4);
  float v[8] = {a.x, a.y, a.z, a.w, b.x, b.y, b.z, b.w};
  uint32 hu[4], lu[4];
#pragma unroll
  for (int j = 0; j < 4; j++) {
    uint32 u0 = __builtin_bit_cast(uint32, v[2 * j]);
    uint32 u1 = __builtin_bit_cast(uint32, v[2 * j + 1]);
    hu[j] = (u0 >> 16) | (u1 & 0xffff0000u);
    float h0 = __builtin_bit_cast(float, u0 & 0xffff0000u);
    float h1 = __builtin_bit_cast(float, u1 & 0xffff0000u);
    float r0 = v[2 * j] - h0;
    float r1 = v[2 * j + 1] - h1;
    lu[j] = (__builtin_bit_cast(uint32, r0) >> 16) |
            (__builtin_bit_cast(uint32, r1) & 0xffff0000u);
  }
  int4 hv = make_int4((int)hu[0], (int)hu[1], (int)hu[2], (int)hu[3]);
  int4 lv = make_int4((int)lu[0], (int)lu[1], (int)lu[2], (int)lu[3]);
  hi = __builtin_bit_cast(bf16x8, hv);
  lo = __builtin_bit_cast(bf16x8, lv);
}

__launch_bounds__(256)
__global__ void sage_dual(const float* __restrict__ agg_d, const float* __restrict__ xd,
                          const float* __restrict__ agg_g, const float* __restrict__ xg,
                          const ushort* __restrict__ WlH, const ushort* __restrict__ WlL,
                          const ushort* __restrict__ WrH, const ushort* __restrict__ WrL,
                          const float* __restrict__ bias_all, float* __restrict__ outd,
                          float* __restrict__ outg, int layer, int relu) {
  __shared__ ushort sW[2][128][40];  // [hi/lo][n][k-chunk 32 + pad 8]

  int b = blockIdx.x;
  const float* AGG;
  const float* X;
  float* O;
  int n, set, r0g;
  if (b < NBT_D) {
    AGG = agg_d; X = xd; O = outd; n = ND; set = layer * 2; r0g = b * 128;
  } else {
    AGG = agg_g; X = xg; O = outg; n = NG; set = layer * 2 + 1; r0g = (b - NBT_D) * 128;
  }
  const ushort* wh[2] = {WlH + set * 16384, WrH + set * 16384};
  const ushort* wl[2] = {WlL + set * 16384, WrL + set * 16384};
  const float* bias = bias_all + set * 128;

  int tid = threadIdx.x;
  int wave = tid >> 6, lane = tid & 63;
  int m = lane & 15, q = lane >> 4;

  // staging map: threads 0-127 stage hi, 128-255 stage lo; 64B per thread
  int ssel = tid >> 7;
  int srow = tid & 127;

  int rc0 = r0g + wave * 32 + m;       // mt=0 row
  int rc1 = rc0 + 16;                  // mt=1 row
  int rw0 = rc0 < n ? rc0 : n - 1;
  int rw1 = rc1 < n ? rc1 : n - 1;

  f32x4 acc[2][8];
#pragma unroll
  for (int mt = 0; mt < 2; mt++)
#pragma unroll
    for (int nt = 0; nt < 8; nt++) acc[mt][nt] = (f32x4)0.f;

#pragma unroll
  for (int ph = 0; ph < 2; ph++) {
    const float* Ab = ph ? X : AGG;
    const float* pr0 = Ab + (size_t)rw0 * DIM;
    const float* pr1 = Ab + (size_t)rw1 * DIM;
    const ushort* wsrc = (ssel ? wl[ph] : wh[ph]) + srow * 128;
#pragma unroll
    for (int ks = 0; ks < 4; ks++) {
      int k0 = ks * 32;
      // issue global loads (W chunk for LDS + A fragments) before the barrier
      const int4* ps = (const int4*)(wsrc + k0);
      int4 w0 = ps[0], w1 = ps[1], w2 = ps[2], w3 = ps[3];
      bf16x8 ah0, al0, ah1, al1;
      cvt_split(pr0 + k0 + q * 8, ah0, al0);
      cvt_split(pr1 + k0 + q * 8, ah1, al1);
      __syncthreads();  // prior iteration's LDS reads complete
      int4* pd = (int4*)&sW[ssel][srow][0];
      pd[0] = w0;
      pd[1] = w1;
      pd[2] = w2;
      pd[3] = w3;
      __syncthreads();
#pragma unroll
      for (int nt = 0; nt < 8; nt++) {
        int nn = nt * 16 + m;
        bf16x8 bh = __builtin_bit_cast(bf16x8, *(const int4*)&sW[0][nn][q * 8]);
        bf16x8 bl = __builtin_bit_cast(bf16x8, *(const int4*)&sW[1][nn][q * 8]);
        acc[0][nt] = __builtin_amdgcn_mfma_f32_16x16x32_bf16(ah0, bh, acc[0][nt], 0, 0, 0);
        acc[1][nt] = __builtin_amdgcn_mfma_f32_16x16x32_bf16(ah1, bh, acc[1][nt], 0, 0, 0);
        acc[0][nt] = __builtin_amdgcn_mfma_f32_16x16x32_bf16(al0, bh, acc[0][nt], 0, 0, 0);
        acc[1][nt] = __builtin_amdgcn_mfma_f32_16x16x32_bf16(al1, bh, acc[1][nt], 0, 0, 0);
        acc[0][nt] = __builtin_amdgcn_mfma_f32_16x16x32_bf16(ah0, bl, acc[0][nt], 0, 0, 0);
        acc[1][nt] = __builtin_amdgcn_mfma_f32_16x16x32_bf16(ah1, bl, acc[1][nt], 0, 0, 0);
      }
    }
  }

  // epilogue: C/D layout: row = q*4 + reg (within 16-tile), col = m
  float bb[8];
#pragma unroll
  for (int nt = 0; nt < 8; nt++) bb[nt] = bias[nt * 16 + m];

#pragma unroll
  for (int mt = 0; mt < 2; mt++) {
#pragma unroll
    for (int reg = 0; reg < 4; reg++) {
      int R = r0g + wave * 32 + mt * 16 + q * 4 + reg;
      float h[8];
      float ss = 0.f;
#pragma unroll
      for (int nt = 0; nt < 8; nt++) {
        float v = acc[mt][nt][reg] + bb[nt];
        if (relu) v = fmaxf(v, 0.f);
        h[nt] = v;
        ss += v * v;
      }
      ss += __shfl_xor(ss, 1);
      ss += __shfl_xor(ss, 2);
      ss += __shfl_xor(ss, 4);
      ss += __shfl_xor(ss, 8);
      if (R < n) {
        float inv = 1.f / fmaxf(sqrtf(ss), EPSN);
        const float* xr = X + (size_t)R * DIM;
        float* orow = O + (size_t)R * DIM;
#pragma unroll
        for (int nt = 0; nt < 8; nt++) {
          int c = nt * 16 + m;
          orow[c] = h[nt] * inv + xr[c];
        }
      }
    }
  }
}

// ---------------- launch ----------------

extern "C" void kernel_launch(void* const* d_in, const int* in_sizes, int n_in,
                              void* d_out, int out_size, void* d_ws, size_t ws_size,
                              hipStream_t stream) {
  const float* xg0 = (const float*)d_in[0];
  const float* xd0 = (const float*)d_in[1];
  const float* Wl = (const float*)d_in[2];   // [L,2,D,D]
  const float* Wr = (const float*)d_in[3];
  const float* bs = (const float*)d_in[4];   // [L,2,D]
  const int* src_g2d = (const int*)d_in[5];
  const int* dst_g2d = (const int*)d_in[6];
  const int* src_d2g = (const int*)d_in[7];
  const int* dst_d2g = (const int*)d_in[8];

  float* out_xg = (float*)d_out;                     // [NG*D]
  float* out_xd = (float*)d_out + (size_t)NG * DIM;  // [ND*D]

  char* p = (char*)d_ws;
  auto alloc = [&](size_t bytes) -> char* {
    char* q = p;
    p += (bytes + 255) & ~(size_t)255;
    return q;
  };
  int* off_d = (int*)alloc((ND + 1) * 4);
  int* off_g = (int*)alloc((NG + 1) * 4);
  int* cur_d = (int*)alloc((size_t)ND * 4);
  int* cur_g = (int*)alloc((size_t)NG * 4);
  int* part = (int*)alloc(512 * 4);
  int* csr_d = (int*)alloc((size_t)NE * 4);
  int* csr_g = (int*)alloc((size_t)NE * 4);
  float* agg_d = (float*)alloc((size_t)ND * DIM * 4);
  float* agg_g = (float*)alloc((size_t)NG * DIM * 4);
  ushort* WlH = (ushort*)alloc((size_t)4 * 128 * 128 * 2);
  ushort* WlL = (ushort*)alloc((size_t)4 * 128 * 128 * 2);
  ushort* WrH = (ushort*)alloc((size_t)4 * 128 * 128 * 2);
  ushort* WrL = (ushort*)alloc((size_t)4 * 128 * 128 * 2);

  const int TB = 256;
  int nbE = (NE + TB - 1) / TB;
  int nbD = (ND + TB - 1) / TB;
  int nbG = (NG + TB - 1) / TB;

  // W split (once per call; tiny)
  split_w<<<256, TB, 0, stream>>>(Wl, Wr, WlH, WlL, WrH, WrL);

  // CSR build
  zero_ints<<<nbD, TB, 0, stream>>>(cur_d, ND);
  zero_ints<<<nbG, TB, 0, stream>>>(cur_g, NG);
  count_deg<<<nbE, TB, 0, stream>>>(dst_g2d, cur_d, NE);
  count_deg<<<nbE, TB, 0, stream>>>(dst_d2g, cur_g, NE);

  block_partials<<<nbD, TB, 0, stream>>>(cur_d, part, ND);
  scan_partials<<<1, 512, 0, stream>>>(part, nbD);
  finalize_scan<<<nbD, TB, 0, stream>>>(cur_d, part, off_d, ND, NE);
  fill_csr<<<nbE, TB, 0, stream>>>(src_g2d, dst_g2d, cur_d, csr_d, NE);

  block_partials<<<nbG, TB, 0, stream>>>(cur_g, part, NG);
  scan_partials<<<1, 512, 0, stream>>>(part, nbG);
  finalize_scan<<<nbG, TB, 0, stream>>>(cur_g, part, off_g, NG, NE);
  fill_csr<<<nbE, TB, 0, stream>>>(src_d2g, dst_d2g, cur_g, csr_g, NE);

  int aggBlocks = (ND + NG) / 4;           // 37500 (one wave per dst node)
  int sageBlocks = NBT_D + NBT_G;          // 1173

  // layer 0 (relu)
  agg_dual<<<aggBlocks, TB, 0, stream>>>(xg0, xd0, off_d, csr_d, agg_d, off_g, csr_g, agg_g);
  sage_dual<<<sageBlocks, TB, 0, stream>>>(agg_d, xd0, agg_g, xg0, WlH, WlL, WrH, WrL, bs,
                                           out_xd, out_xg, 0, 1);

  // layer 1 (no relu), in-place on d_out
  agg_dual<<<aggBlocks, TB, 0, stream>>>(out_xg, out_xd, off_d, csr_d, agg_d, off_g, csr_g,
                                         agg_g);
  sage_dual<<<sageBlocks, TB, 0, stream>>>(agg_d, out_xd, agg_g, out_xg, WlH, WlL, WrH, WrL,
                                           bs, out_xd, out_xg, 1, 0);
}

// Round 3
// 625.997 us; speedup vs baseline: 1.8971x; 1.0487x over previous
//
#include <hip/hip_runtime.h>
#include <math.h>

#define NG 100000
#define ND 50000
#define DIM 128
#define NE 800000
#define EPSN 1e-12f

#define NBT_D 391  // ceil(ND/128)
#define NBT_G 782  // ceil(NG/128)

typedef __bf16 bf16x8 __attribute__((ext_vector_type(8)));
typedef float f32x4 __attribute__((ext_vector_type(4)));
typedef unsigned int uint32;

__device__ __forceinline__ ushort rne_bf16(float f) {
  uint32 u = __builtin_bit_cast(uint32, f);
  u += 0x7fffu + ((u >> 16) & 1u);
  return (ushort)(u >> 16);
}

// ---------------- CSR build helpers ----------------

__global__ void zero_ints(int* __restrict__ p, int n) {
  int i = blockIdx.x * 256 + threadIdx.x;
  if (i < n) p[i] = 0;
}

__global__ void count_deg(const int* __restrict__ dst, int* __restrict__ deg, int n) {
  int i = blockIdx.x * 256 + threadIdx.x;
  if (i < n) atomicAdd(&deg[dst[i]], 1);
}

__global__ void block_partials(const int* __restrict__ deg, int* __restrict__ part, int n) {
  __shared__ int s[256];
  int i = blockIdx.x * 256 + threadIdx.x;
  s[threadIdx.x] = (i < n) ? deg[i] : 0;
  __syncthreads();
  for (int st = 128; st > 0; st >>= 1) {
    if (threadIdx.x < st) s[threadIdx.x] += s[threadIdx.x + st];
    __syncthreads();
  }
  if (threadIdx.x == 0) part[blockIdx.x] = s[0];
}

__global__ void scan_partials(int* __restrict__ part, int nb) {
  __shared__ int s[512];
  int t = threadIdx.x;
  s[t] = (t < nb) ? part[t] : 0;
  __syncthreads();
  for (int off = 1; off < 512; off <<= 1) {
    int v = (t >= off) ? s[t - off] : 0;
    __syncthreads();
    s[t] += v;
    __syncthreads();
  }
  if (t < nb) part[t] = (t > 0) ? s[t - 1] : 0;
}

__global__ void finalize_scan(int* __restrict__ deg_cur, const int* __restrict__ part,
                              int* __restrict__ off, int n, int total) {
  __shared__ int s[256];
  int t = threadIdx.x;
  int i = blockIdx.x * 256 + t;
  int d = (i < n) ? deg_cur[i] : 0;
  s[t] = d;
  __syncthreads();
  for (int o = 1; o < 256; o <<= 1) {
    int v = (t >= o) ? s[t - o] : 0;
    __syncthreads();
    s[t] += v;
    __syncthreads();
  }
  int excl = s[t] - d + part[blockIdx.x];
  if (i < n) {
    off[i] = excl;
    deg_cur[i] = excl;
    if (i == n - 1) off[n] = total;
  }
}

__global__ void fill_csr(const int* __restrict__ src, const int* __restrict__ dst,
                         int* __restrict__ cur, int* __restrict__ csr, int n) {
  int i = blockIdx.x * 256 + threadIdx.x;
  if (i < n) {
    int p = atomicAdd(&cur[dst[i]], 1);
    csr[p] = src[i];
  }
}

// ---------------- fp32 -> bf16 table convert (RNE) ----------------

__global__ void to_bf16(const float* __restrict__ x, ushort* __restrict__ y, int n8) {
  int i = blockIdx.x * 256 + threadIdx.x;
  if (i >= n8) return;
  const float4* px = (const float4*)x;
  float4 a = px[2 * i], b = px[2 * i + 1];
  float v[8] = {a.x, a.y, a.z, a.w, b.x, b.y, b.z, b.w};
  uint32 u[4];
#pragma unroll
  for (int j = 0; j < 4; j++) {
    u[j] = (uint32)rne_bf16(v[2 * j]) | ((uint32)rne_bf16(v[2 * j + 1]) << 16);
  }
  ((int4*)y)[i] = make_int4((int)u[0], (int)u[1], (int)u[2], (int)u[3]);
}

// ---------------- W pre-split: fp32 -> bf16 hi + bf16 lo (truncate split) ----------------

__global__ void split_w(const float* __restrict__ Wl, const float* __restrict__ Wr,
                        ushort* __restrict__ WlH, ushort* __restrict__ WlL,
                        ushort* __restrict__ WrH, ushort* __restrict__ WrL) {
  int i = blockIdx.x * 256 + threadIdx.x;
  if (i >= 4 * 128 * 128) return;
  {
    float a = Wl[i];
    uint32 u = __builtin_bit_cast(uint32, a);
    float hf = __builtin_bit_cast(float, u & 0xffff0000u);
    float r = a - hf;
    WlH[i] = (ushort)(u >> 16);
    WlL[i] = (ushort)(__builtin_bit_cast(uint32, r) >> 16);
  }
  {
    float a = Wr[i];
    uint32 u = __builtin_bit_cast(uint32, a);
    float hf = __builtin_bit_cast(float, u & 0xffff0000u);
    float r = a - hf;
    WrH[i] = (ushort)(u >> 16);
    WrL[i] = (ushort)(__builtin_bit_cast(uint32, r) >> 16);
  }
}

// ---------------- mean aggregation over bf16 rows ----------------
// One wave per dst node. Quarter-waves: 16 lanes x 16B = one full 256B bf16 row,
// 4 edges per wave-instruction, unroll 2 -> 8 edges in flight. fp32 accumulate,
// bf16 (RNE) output.

__device__ __forceinline__ void acc8(float* a, int4 u) {
  uint32 w;
  w = (uint32)u.x;
  a[0] += __builtin_bit_cast(float, w << 16);
  a[1] += __builtin_bit_cast(float, w & 0xffff0000u);
  w = (uint32)u.y;
  a[2] += __builtin_bit_cast(float, w << 16);
  a[3] += __builtin_bit_cast(float, w & 0xffff0000u);
  w = (uint32)u.z;
  a[4] += __builtin_bit_cast(float, w << 16);
  a[5] += __builtin_bit_cast(float, w & 0xffff0000u);
  w = (uint32)u.w;
  a[6] += __builtin_bit_cast(float, w << 16);
  a[7] += __builtin_bit_cast(float, w & 0xffff0000u);
}

__global__ void agg_dual_bf(const ushort* __restrict__ xg_bf, const ushort* __restrict__ xd_bf,
                            const int* __restrict__ off_d, const int* __restrict__ csr_d,
                            ushort* __restrict__ agg_d,
                            const int* __restrict__ off_g, const int* __restrict__ csr_g,
                            ushort* __restrict__ agg_g) {
  int gw = (blockIdx.x * 256 + threadIdx.x) >> 6;
  int lane = threadIdx.x & 63;
  const ushort* xsrc;
  const int* off;
  const int* csr;
  ushort* agg;
  int node;
  if (gw < ND) {
    xsrc = xg_bf; off = off_d; csr = csr_d; agg = agg_d; node = gw;
  } else {
    node = gw - ND;
    if (node >= NG) return;
    xsrc = xd_bf; off = off_g; csr = csr_g; agg = agg_g;
  }
  int e0 = off[node], e1 = off[node + 1];
  int q = lane >> 4, l16 = lane & 15;
  const int4* xs = (const int4*)xsrc;  // one row = 16 int4
  float a[8] = {0.f, 0.f, 0.f, 0.f, 0.f, 0.f, 0.f, 0.f};
  int e = e0 + q;
  for (; e + 4 < e1; e += 8) {
    int s0 = csr[e], s1 = csr[e + 4];
    int4 u = xs[(size_t)s0 * 16 + l16];
    int4 v = xs[(size_t)s1 * 16 + l16];
    acc8(a, u);
    acc8(a, v);
  }
  if (e < e1) {
    int4 u = xs[(size_t)csr[e] * 16 + l16];
    acc8(a, u);
  }
#pragma unroll
  for (int j = 0; j < 8; j++) {
    a[j] += __shfl_xor(a[j], 16);
    a[j] += __shfl_xor(a[j], 32);
  }
  if (q == 0) {
    int deg = e1 - e0;
    float inv = (deg > 0) ? 1.f / (float)deg : 0.f;
    uint32 u[4];
#pragma unroll
    for (int j = 0; j < 4; j++) {
      u[j] = (uint32)rne_bf16(a[2 * j] * inv) | ((uint32)rne_bf16(a[2 * j + 1] * inv) << 16);
    }
    *(int4*)&agg[(size_t)node * DIM + l16 * 8] =
        make_int4((int)u[0], (int)u[1], (int)u[2], (int)u[3]);
  }
}

// ---------------- split-bf16 MFMA SAGE update ----------------
// Per block: 128 rows x 128 cols. C = aggbf*Wl^T + x*Wr^T; agg operand is bf16
// (2 MFMAs: Ah*Bh + Ah*Bl), x operand split hi/lo (3 MFMAs). Epilogue: +bias,
// (relu), row l2-norm, skip-add x, optional bf16 copy of out for next layer's gather.

__device__ __forceinline__ void cvt_split(const float* p, bf16x8& hi, bf16x8& lo) {
  float4 a = *(const float4*)p;
  float4 b = *(const float4*)(p + 4);
  float v[8] = {a.x, a.y, a.z, a.w, b.x, b.y, b.z, b.w};
  uint32 hu[4], lu[4];
#pragma unroll
  for (int j = 0; j < 4; j++) {
    uint32 u0 = __builtin_bit_cast(uint32, v[2 * j]);
    uint32 u1 = __builtin_bit_cast(uint32, v[2 * j + 1]);
    hu[j] = (u0 >> 16) | (u1 & 0xffff0000u);
    float h0 = __builtin_bit_cast(float, u0 & 0xffff0000u);
    float h1 = __builtin_bit_cast(float, u1 & 0xffff0000u);
    float r0 = v[2 * j] - h0;
    float r1 = v[2 * j + 1] - h1;
    lu[j] = (__builtin_bit_cast(uint32, r0) >> 16) |
            (__builtin_bit_cast(uint32, r1) & 0xffff0000u);
  }
  int4 hv = make_int4((int)hu[0], (int)hu[1], (int)hu[2], (int)hu[3]);
  int4 lv = make_int4((int)lu[0], (int)lu[1], (int)lu[2], (int)lu[3]);
  hi = __builtin_bit_cast(bf16x8, hv);
  lo = __builtin_bit_cast(bf16x8, lv);
}

__launch_bounds__(256)
__global__ void sage_dual(const ushort* __restrict__ agg_d, const float* __restrict__ xd,
                          const ushort* __restrict__ agg_g, const float* __restrict__ xg,
                          const ushort* __restrict__ WlH, const ushort* __restrict__ WlL,
                          const ushort* __restrict__ WrH, const ushort* __restrict__ WrL,
                          const float* __restrict__ bias_all, float* __restrict__ outd,
                          float* __restrict__ outg, ushort* __restrict__ xbf_d,
                          ushort* __restrict__ xbf_g, int layer, int relu, int write_bf) {
  __shared__ ushort sW[2][128][40];  // [hi/lo][n][k-chunk 32 + pad 8]

  int b = blockIdx.x;
  const ushort* AGG;
  const float* X;
  float* O;
  ushort* OBF;
  int n, set, r0g;
  if (b < NBT_D) {
    AGG = agg_d; X = xd; O = outd; OBF = xbf_d; n = ND; set = layer * 2; r0g = b * 128;
  } else {
    AGG = agg_g; X = xg; O = outg; OBF = xbf_g; n = NG; set = layer * 2 + 1;
    r0g = (b - NBT_D) * 128;
  }
  const ushort* wh[2] = {WlH + set * 16384, WrH + set * 16384};
  const ushort* wl[2] = {WlL + set * 16384, WrL + set * 16384};
  const float* bias = bias_all + set * 128;

  int tid = threadIdx.x;
  int wave = tid >> 6, lane = tid & 63;
  int m = lane & 15, q = lane >> 4;

  int ssel = tid >> 7;  // 0: hi plane, 1: lo plane
  int srow = tid & 127;

  int rc0 = r0g + wave * 32 + m;
  int rc1 = rc0 + 16;
  int rw0 = rc0 < n ? rc0 : n - 1;
  int rw1 = rc1 < n ? rc1 : n - 1;

  f32x4 acc[2][8];
#pragma unroll
  for (int mt = 0; mt < 2; mt++)
#pragma unroll
    for (int nt = 0; nt < 8; nt++) acc[mt][nt] = (f32x4)0.f;

#pragma unroll
  for (int ph = 0; ph < 2; ph++) {
    const ushort* wsrc = (ssel ? wl[ph] : wh[ph]) + srow * 128;
#pragma unroll
    for (int ks = 0; ks < 4; ks++) {
      int k0 = ks * 32;
      const int4* ps = (const int4*)(wsrc + k0);
      int4 w0 = ps[0], w1 = ps[1], w2 = ps[2], w3 = ps[3];
      bf16x8 ah0, al0, ah1, al1;
      if (ph == 0) {
        ah0 = __builtin_bit_cast(bf16x8, *(const int4*)&AGG[(size_t)rw0 * DIM + k0 + q * 8]);
        ah1 = __builtin_bit_cast(bf16x8, *(const int4*)&AGG[(size_t)rw1 * DIM + k0 + q * 8]);
        al0 = ah0;  // unused
        al1 = ah1;
      } else {
        cvt_split(X + (size_t)rw0 * DIM + k0 + q * 8, ah0, al0);
        cvt_split(X + (size_t)rw1 * DIM + k0 + q * 8, ah1, al1);
      }
      __syncthreads();
      int4* pd = (int4*)&sW[ssel][srow][0];
      pd[0] = w0;
      pd[1] = w1;
      pd[2] = w2;
      pd[3] = w3;
      __syncthreads();
#pragma unroll
      for (int nt = 0; nt < 8; nt++) {
        int nn = nt * 16 + m;
        bf16x8 bh = __builtin_bit_cast(bf16x8, *(const int4*)&sW[0][nn][q * 8]);
        bf16x8 bl = __builtin_bit_cast(bf16x8, *(const int4*)&sW[1][nn][q * 8]);
        acc[0][nt] = __builtin_amdgcn_mfma_f32_16x16x32_bf16(ah0, bh, acc[0][nt], 0, 0, 0);
        acc[1][nt] = __builtin_amdgcn_mfma_f32_16x16x32_bf16(ah1, bh, acc[1][nt], 0, 0, 0);
        acc[0][nt] = __builtin_amdgcn_mfma_f32_16x16x32_bf16(ah0, bl, acc[0][nt], 0, 0, 0);
        acc[1][nt] = __builtin_amdgcn_mfma_f32_16x16x32_bf16(ah1, bl, acc[1][nt], 0, 0, 0);
        if (ph == 1) {
          acc[0][nt] = __builtin_amdgcn_mfma_f32_16x16x32_bf16(al0, bh, acc[0][nt], 0, 0, 0);
          acc[1][nt] = __builtin_amdgcn_mfma_f32_16x16x32_bf16(al1, bh, acc[1][nt], 0, 0, 0);
        }
      }
    }
  }

  // epilogue: C/D layout: row = q*4 + reg (within 16-tile), col = m
  float bb[8];
#pragma unroll
  for (int nt = 0; nt < 8; nt++) bb[nt] = bias[nt * 16 + m];

#pragma unroll
  for (int mt = 0; mt < 2; mt++) {
#pragma unroll
    for (int reg = 0; reg < 4; reg++) {
      int R = r0g + wave * 32 + mt * 16 + q * 4 + reg;
      float h[8];
      float ss = 0.f;
#pragma unroll
      for (int nt = 0; nt < 8; nt++) {
        float v = acc[mt][nt][reg] + bb[nt];
        if (relu) v = fmaxf(v, 0.f);
        h[nt] = v;
        ss += v * v;
      }
      ss += __shfl_xor(ss, 1);
      ss += __shfl_xor(ss, 2);
      ss += __shfl_xor(ss, 4);
      ss += __shfl_xor(ss, 8);
      if (R < n) {
        float inv = 1.f / fmaxf(sqrtf(ss), EPSN);
        const float* xr = X + (size_t)R * DIM;
        float* orow = O + (size_t)R * DIM;
        ushort* obf = OBF + (size_t)R * DIM;
#pragma unroll
        for (int nt = 0; nt < 8; nt++) {
          int c = nt * 16 + m;
          float o = h[nt] * inv + xr[c];
          orow[c] = o;
          if (write_bf) obf[c] = rne_bf16(o);
        }
      }
    }
  }
}

// ---------------- launch ----------------

extern "C" void kernel_launch(void* const* d_in, const int* in_sizes, int n_in,
                              void* d_out, int out_size, void* d_ws, size_t ws_size,
                              hipStream_t stream) {
  const float* xg0 = (const float*)d_in[0];
  const float* xd0 = (const float*)d_in[1];
  const float* Wl = (const float*)d_in[2];
  const float* Wr = (const float*)d_in[3];
  const float* bs = (const float*)d_in[4];
  const int* src_g2d = (const int*)d_in[5];
  const int* dst_g2d = (const int*)d_in[6];
  const int* src_d2g = (const int*)d_in[7];
  const int* dst_d2g = (const int*)d_in[8];

  float* out_xg = (float*)d_out;
  float* out_xd = (float*)d_out + (size_t)NG * DIM;

  char* p = (char*)d_ws;
  auto alloc = [&](size_t bytes) -> char* {
    char* q = p;
    p += (bytes + 255) & ~(size_t)255;
    return q;
  };
  int* off_d = (int*)alloc((ND + 1) * 4);
  int* off_g = (int*)alloc((NG + 1) * 4);
  int* cur_d = (int*)alloc((size_t)ND * 4);
  int* cur_g = (int*)alloc((size_t)NG * 4);
  int* part = (int*)alloc(512 * 4);
  int* csr_d = (int*)alloc((size_t)NE * 4);
  int* csr_g = (int*)alloc((size_t)NE * 4);
  ushort* agg_d_bf = (ushort*)alloc((size_t)ND * DIM * 2);
  ushort* agg_g_bf = (ushort*)alloc((size_t)NG * DIM * 2);
  ushort* xg_bf = (ushort*)alloc((size_t)NG * DIM * 2);
  ushort* xd_bf = (ushort*)alloc((size_t)ND * DIM * 2);
  ushort* WlH = (ushort*)alloc((size_t)4 * 128 * 128 * 2);
  ushort* WlL = (ushort*)alloc((size_t)4 * 128 * 128 * 2);
  ushort* WrH = (ushort*)alloc((size_t)4 * 128 * 128 * 2);
  ushort* WrL = (ushort*)alloc((size_t)4 * 128 * 128 * 2);

  const int TB = 256;
  int nbE = (NE + TB - 1) / TB;
  int nbD = (ND + TB - 1) / TB;
  int nbG = (NG + TB - 1) / TB;

  split_w<<<256, TB, 0, stream>>>(Wl, Wr, WlH, WlL, WrH, WrL);
  to_bf16<<<(NG * 16 + TB - 1) / TB, TB, 0, stream>>>(xg0, xg_bf, NG * 16);
  to_bf16<<<(ND * 16 + TB - 1) / TB, TB, 0, stream>>>(xd0, xd_bf, ND * 16);

  zero_ints<<<nbD, TB, 0, stream>>>(cur_d, ND);
  zero_ints<<<nbG, TB, 0, stream>>>(cur_g, NG);
  count_deg<<<nbE, TB, 0, stream>>>(dst_g2d, cur_d, NE);
  count_deg<<<nbE, TB, 0, stream>>>(dst_d2g, cur_g, NE);

  block_partials<<<nbD, TB, 0, stream>>>(cur_d, part, ND);
  scan_partials<<<1, 512, 0, stream>>>(part, nbD);
  finalize_scan<<<nbD, TB, 0, stream>>>(cur_d, part, off_d, ND, NE);
  fill_csr<<<nbE, TB, 0, stream>>>(src_g2d, dst_g2d, cur_d, csr_d, NE);

  block_partials<<<nbG, TB, 0, stream>>>(cur_g, part, NG);
  scan_partials<<<1, 512, 0, stream>>>(part, nbG);
  finalize_scan<<<nbG, TB, 0, stream>>>(cur_g, part, off_g, NG, NE);
  fill_csr<<<nbE, TB, 0, stream>>>(src_d2g, dst_d2g, cur_g, csr_g, NE);

  int aggBlocks = (ND + NG) / 4;
  int sageBlocks = NBT_D + NBT_G;

  // layer 0 (relu); sage also emits bf16 copy of out for layer-1 gather
  agg_dual_bf<<<aggBlocks, TB, 0, stream>>>(xg_bf, xd_bf, off_d, csr_d, agg_d_bf, off_g,
                                            csr_g, agg_g_bf);
  sage_dual<<<sageBlocks, TB, 0, stream>>>(agg_d_bf, xd0, agg_g_bf, xg0, WlH, WlL, WrH, WrL,
                                           bs, out_xd, out_xg, xd_bf, xg_bf, 0, 1, 1);

  // layer 1 (no relu), in-place on d_out
  agg_dual_bf<<<aggBlocks, TB, 0, stream>>>(xg_bf, xd_bf, off_d, csr_d, agg_d_bf, off_g,
                                            csr_g, agg_g_bf);
  sage_dual<<<sageBlocks, TB, 0, stream>>>(agg_d_bf, out_xd, agg_g_bf, out_xg, WlH, WlL, WrH,
                                           WrL, bs, out_xd, out_xg, xd_bf, xg_bf, 1, 0, 0);
}